// Round 1
// baseline (369.715 us; speedup 1.0000x reference)
//
#include <hip/hip_runtime.h>
#include <math.h>

// iSQRT-COV pooling: B=64, C=128, n=56*56=3136
// sigma = (1/n) * Xc Xc^T  computed as  G/n - mu mu^T  (G = X X^T, mu = rowmean)
// Newton-Schulz 5 iters on A = sigma/tr(sigma); out = triu(Y * sqrt(tr))

#define CC 128
#define NN 3136
#define BB 64
#define KSPLIT 4
#define KCHUNK 784           // NN / KSPLIT, multiple of 16
#define MATS (CC * CC)       // 16384
#define OUTLEN 8256          // 128*129/2

// ---------------------------------------------------------------------------
// Gram partial: grid (B, KSPLIT), block 256 (16x16 threads, 8x8 regs each).
// Computes Gpart[ks][b] = X[:, ks-chunk] @ X[:, ks-chunk]^T and partial rowsums.
// ---------------------------------------------------------------------------
__global__ __launch_bounds__(256)
void gram_kernel(const float* __restrict__ x, float* __restrict__ Gpart,
                 float* __restrict__ rspart)
{
    __shared__ float Xs[16][CC + 2];
    const int b   = blockIdx.x;
    const int ks  = blockIdx.y;
    const int tid = threadIdx.x;
    const int ty  = tid >> 4, tx = tid & 15;
    const float* __restrict__ X = x + (size_t)b * CC * NN;
    const int k0 = ks * KCHUNK;

    float acc[8][8];
#pragma unroll
    for (int u = 0; u < 8; ++u)
#pragma unroll
        for (int v = 0; v < 8; ++v) acc[u][v] = 0.f;
    float rsum = 0.f;

    const int r0 = tid >> 2;          // 0..63
    const int kk = (tid & 3) << 2;    // 0,4,8,12

    for (int kt = 0; kt < KCHUNK; kt += 16) {
#pragma unroll
        for (int h = 0; h < 2; ++h) {
            const int row = h * 64 + r0;
            const float4 v = *(const float4*)(X + (size_t)row * NN + k0 + kt + kk);
            Xs[kk + 0][row] = v.x;
            Xs[kk + 1][row] = v.y;
            Xs[kk + 2][row] = v.z;
            Xs[kk + 3][row] = v.w;
        }
        __syncthreads();
        if (tid < CC) {
#pragma unroll
            for (int k = 0; k < 16; ++k) rsum += Xs[k][tid];
        }
#pragma unroll
        for (int k = 0; k < 16; ++k) {
            float a[8], bb[8];
#pragma unroll
            for (int u = 0; u < 8; ++u) a[u] = Xs[k][ty * 8 + u];
#pragma unroll
            for (int v = 0; v < 8; ++v) bb[v] = Xs[k][tx * 8 + v];
#pragma unroll
            for (int u = 0; u < 8; ++u)
#pragma unroll
                for (int v = 0; v < 8; ++v)
                    acc[u][v] += a[u] * bb[v];
        }
        __syncthreads();
    }

    float* __restrict__ Gb = Gpart + ((size_t)ks * BB + b) * MATS;
#pragma unroll
    for (int u = 0; u < 8; ++u) {
#pragma unroll
        for (int v = 0; v < 8; v += 4) {
            float4 w = make_float4(acc[u][v], acc[u][v + 1], acc[u][v + 2], acc[u][v + 3]);
            *(float4*)(Gb + (size_t)(ty * 8 + u) * CC + tx * 8 + v) = w;
        }
    }
    if (tid < CC) rspart[((size_t)ks * BB + b) * CC + tid] = rsum;
}

// ---------------------------------------------------------------------------
// Finalize: sum partials, sigma = G/n - mu mu^T, tr = trace(sigma),
// Y0 = sigma/tr, Z0 = I. Grid (B), block 256.
// ---------------------------------------------------------------------------
__global__ __launch_bounds__(256)
void finalize_kernel(const float* __restrict__ Gpart, const float* __restrict__ rspart,
                     float* __restrict__ Y0, float* __restrict__ Z0,
                     float* __restrict__ tr)
{
    __shared__ float mu[CC];
    __shared__ float redbuf[256];
    __shared__ float tr_s;
    const int b   = blockIdx.x;
    const int tid = threadIdx.x;

    if (tid < CC) {
        float s = 0.f;
#pragma unroll
        for (int ks = 0; ks < KSPLIT; ++ks)
            s += rspart[((size_t)ks * BB + b) * CC + tid];
        mu[tid] = s * (1.0f / NN);
    }
    __syncthreads();

    float tsum = 0.f;
    if (tid < CC) {
        float g = 0.f;
#pragma unroll
        for (int ks = 0; ks < KSPLIT; ++ks)
            g += Gpart[((size_t)ks * BB + b) * MATS + (size_t)tid * (CC + 1)];
        tsum = g * (1.0f / NN) - mu[tid] * mu[tid];
    }
    redbuf[tid] = tsum;
    __syncthreads();
    for (int s2 = 128; s2 > 0; s2 >>= 1) {
        if (tid < s2) redbuf[tid] += redbuf[tid + s2];
        __syncthreads();
    }
    if (tid == 0) { tr[b] = redbuf[0]; tr_s = redbuf[0]; }
    __syncthreads();

    const float inv_tr = 1.0f / tr_s;
    for (int idx = tid; idx < MATS; idx += 256) {
        const int i = idx >> 7, j = idx & 127;
        float g = 0.f;
#pragma unroll
        for (int ks = 0; ks < KSPLIT; ++ks)
            g += Gpart[((size_t)ks * BB + b) * MATS + idx];
        const float a = (g * (1.0f / NN) - mu[i] * mu[j]) * inv_tr;
        Y0[(size_t)b * MATS + idx] = a;
        Z0[(size_t)b * MATS + idx] = (i == j) ? 1.0f : 0.0f;
    }
}

// ---------------------------------------------------------------------------
// Tiled 64x64x128 matmul core: block 256 threads (16x16), 4x4 regs/thread.
// ---------------------------------------------------------------------------
__device__ __forceinline__
void mm_tile(const float* __restrict__ L, const float* __restrict__ R,
             int i0, int j0, float (*Ls)[68], float (*Rs)[68], float acc[4][4])
{
    const int tid = threadIdx.x;
    const int ty = tid >> 4, tx = tid & 15;
    const int r  = tid >> 2;            // 0..63  (L load)
    const int kkL = (tid & 3) << 2;     // 0,4,8,12
    const int rr = tid >> 4;            // 0..15  (R load)
    const int cc = (tid & 15) << 2;     // 0..60

    for (int k0 = 0; k0 < CC; k0 += 16) {
        const float4 v = *(const float4*)(L + (size_t)(i0 + r) * CC + k0 + kkL);
        Ls[kkL + 0][r] = v.x;
        Ls[kkL + 1][r] = v.y;
        Ls[kkL + 2][r] = v.z;
        Ls[kkL + 3][r] = v.w;
        const float4 w = *(const float4*)(R + (size_t)(k0 + rr) * CC + j0 + cc);
        *(float4*)&Rs[rr][cc] = w;
        __syncthreads();
#pragma unroll
        for (int k = 0; k < 16; ++k) {
            float a[4], bb[4];
#pragma unroll
            for (int u = 0; u < 4; ++u) a[u] = Ls[k][ty * 4 + u];
#pragma unroll
            for (int v2 = 0; v2 < 4; ++v2) bb[v2] = Rs[k][tx * 4 + v2];
#pragma unroll
            for (int u = 0; u < 4; ++u)
#pragma unroll
                for (int v2 = 0; v2 < 4; ++v2)
                    acc[u][v2] += a[u] * bb[v2];
        }
        __syncthreads();
    }
}

// T = 0.5*(3I - Z@Y). Grid (B, 4): tile = (y>>1, y&1) of 64x64.
__global__ __launch_bounds__(256)
void ns_t_kernel(const float* __restrict__ Z, const float* __restrict__ Y,
                 float* __restrict__ T)
{
    __shared__ float Ls[16][68];
    __shared__ float Rs[16][68];
    const int b = blockIdx.x, t = blockIdx.y;
    const int i0 = (t >> 1) * 64, j0 = (t & 1) * 64;
    const float* Zb = Z + (size_t)b * MATS;
    const float* Yb = Y + (size_t)b * MATS;
    float acc[4][4] = {};
    mm_tile(Zb, Yb, i0, j0, Ls, Rs, acc);
    const int ty = (threadIdx.x >> 4), tx = (threadIdx.x & 15);
    float* Tb = T + (size_t)b * MATS;
#pragma unroll
    for (int u = 0; u < 4; ++u)
#pragma unroll
        for (int v = 0; v < 4; ++v) {
            const int i = i0 + ty * 4 + u, j = j0 + tx * 4 + v;
            Tb[(size_t)i * CC + j] = 0.5f * (((i == j) ? 3.0f : 0.0f) - acc[u][v]);
        }
}

// Ynew = Y@T (y<4), Znew = T@Z (y>=4). Grid (B, 8).
__global__ __launch_bounds__(256)
void ns_yz_kernel(const float* __restrict__ Y, const float* __restrict__ Z,
                  const float* __restrict__ T,
                  float* __restrict__ Yn, float* __restrict__ Zn)
{
    __shared__ float Ls[16][68];
    __shared__ float Rs[16][68];
    const int b = blockIdx.x, s = blockIdx.y;
    const int op = s >> 2, t = s & 3;
    const int i0 = (t >> 1) * 64, j0 = (t & 1) * 64;
    const float* L;
    const float* R;
    float* O;
    if (op == 0) { L = Y + (size_t)b * MATS; R = T + (size_t)b * MATS; O = Yn + (size_t)b * MATS; }
    else         { L = T + (size_t)b * MATS; R = Z + (size_t)b * MATS; O = Zn + (size_t)b * MATS; }
    float acc[4][4] = {};
    mm_tile(L, R, i0, j0, Ls, Rs, acc);
    const int ty = (threadIdx.x >> 4), tx = (threadIdx.x & 15);
#pragma unroll
    for (int u = 0; u < 4; ++u) {
        const int i = i0 + ty * 4 + u;
#pragma unroll
        for (int v = 0; v < 4; ++v)
            O[(size_t)i * CC + j0 + tx * 4 + v] = acc[u][v];
    }
}

// out[b][k] = Y[i][j] * sqrt(tr[b]), triu row-major mapping. Grid (B).
__global__ __launch_bounds__(256)
void triu_kernel(const float* __restrict__ Y, const float* __restrict__ tr,
                 float* __restrict__ out)
{
    const int b = blockIdx.x;
    const float s = sqrtf(tr[b]);
    const float* Yb = Y + (size_t)b * MATS;
    for (int k = threadIdx.x; k < OUTLEN; k += 256) {
        int i = (int)((257.0f - sqrtf(66049.0f - 8.0f * (float)k)) * 0.5f);
        if (i < 0) i = 0;
        if (i > 127) i = 127;
        while (i < 127 && (((i + 1) * (257 - (i + 1))) >> 1) <= k) ++i;
        while (i > 0 && ((i * (257 - i)) >> 1) > k) --i;
        const int j = i + (k - ((i * (257 - i)) >> 1));
        out[(size_t)b * OUTLEN + k] = Yb[(size_t)i * CC + j] * s;
    }
}

extern "C" void kernel_launch(void* const* d_in, const int* in_sizes, int n_in,
                              void* d_out, int out_size, void* d_ws, size_t ws_size,
                              hipStream_t stream)
{
    const float* x = (const float*)d_in[0];
    float* out = (float*)d_out;
    float* ws  = (float*)d_ws;

    float* tr     = ws;                                   // 64
    float* rspart = ws + 64;                              // KSPLIT*BB*CC = 32768
    float* Gpart  = rspart + (size_t)KSPLIT * BB * CC;    // KSPLIT*BB*MATS
    float* Y0     = Gpart + (size_t)KSPLIT * BB * MATS;
    float* Z0     = Y0 + (size_t)BB * MATS;
    float* Y1     = Z0 + (size_t)BB * MATS;
    float* Z1     = Y1 + (size_t)BB * MATS;
    float* Tm     = Z1 + (size_t)BB * MATS;

    gram_kernel<<<dim3(BB, KSPLIT), 256, 0, stream>>>(x, Gpart, rspart);
    finalize_kernel<<<dim3(BB), 256, 0, stream>>>(Gpart, rspart, Y0, Z0, tr);

    float* Yc = Y0; float* Zc = Z0; float* Yn = Y1; float* Zn = Z1;
    for (int it = 0; it < 5; ++it) {
        ns_t_kernel<<<dim3(BB, 4), 256, 0, stream>>>(Zc, Yc, Tm);
        ns_yz_kernel<<<dim3(BB, 8), 256, 0, stream>>>(Yc, Zc, Tm, Yn, Zn);
        float* t1 = Yc; Yc = Yn; Yn = t1;
        float* t2 = Zc; Zc = Zn; Zn = t2;
    }

    triu_kernel<<<dim3(BB), 256, 0, stream>>>(Yc, tr, out);
}

// Round 2
// 200.851 us; speedup vs baseline: 1.8407x; 1.8407x over previous
//
#include <hip/hip_runtime.h>
#include <math.h>

// iSQRT-COV: B=64, C=128, n=3136.
// sigma = G/n - mu mu^T (G = X X^T via split-bf16 MFMA),
// fused Newton-Schulz (5 iters) entirely in LDS, one block per batch.

#define CC 128
#define NN 3136
#define BB 64
#define KS 7
#define KCHUNK 448            // NN/KS = 14 ksteps of 32
#define MATS (CC * CC)
#define OUTLEN 8256
#define PSTR 136              // plane row stride in bf16 (17 granules -> conflict-safe)
#define SSTR 40               // gram stage row stride in bf16

typedef float f32x4 __attribute__((ext_vector_type(4)));
typedef short s16x8 __attribute__((ext_vector_type(8)));
typedef short s16x4 __attribute__((ext_vector_type(4)));
typedef __bf16 bf16x8 __attribute__((ext_vector_type(8)));

__device__ __forceinline__ unsigned short f2b(float f) {
    unsigned u = __builtin_bit_cast(unsigned, f);
    unsigned r = u + 0x7fffu + ((u >> 16) & 1u);
    return (unsigned short)(r >> 16);
}
__device__ __forceinline__ float b2f(unsigned short s) {
    return __builtin_bit_cast(float, ((unsigned)s) << 16);
}

__device__ __forceinline__ f32x4 MF(s16x8 a, s16x8 b, f32x4 c) {
    return __builtin_amdgcn_mfma_f32_16x16x32_bf16(
        __builtin_bit_cast(bf16x8, a), __builtin_bit_cast(bf16x8, b), c, 0, 0, 0);
}

// ---------------------------------------------------------------------------
// Gram partial via split-bf16 MFMA. grid (BB, KS), block 256 (4 waves).
// Gpart[ks*BB+b] = X[:,chunk] @ X[:,chunk]^T (fp32); rspart = partial rowsums.
// ---------------------------------------------------------------------------
__global__ __launch_bounds__(256, 1)
void gram_kernel(const float* __restrict__ x, float* __restrict__ Gpart,
                 float* __restrict__ rspart)
{
    __shared__ short Xs[2][2][128 * SSTR];   // [buf][hi/lo][row*SSTR+k]
    const int b = blockIdx.x, ks = blockIdx.y;
    const int tid  = threadIdx.x;
    const int wave = tid >> 6, lane = tid & 63;
    const int q = lane >> 4, l15 = lane & 15;
    const int i0 = (wave >> 1) * 64, j0 = (wave & 1) * 64;

    const float* __restrict__ Xb = x + (size_t)b * CC * NN + (size_t)ks * KCHUNK;
    const int lrow = tid >> 3;        // 0..31
    const int lf   = tid & 7;         // 0..7

    f32x4 acc[4][4];
#pragma unroll
    for (int rt = 0; rt < 4; ++rt)
#pragma unroll
        for (int ct = 0; ct < 4; ++ct) acc[rt][ct] = (f32x4){0.f, 0.f, 0.f, 0.f};
    float rs[4] = {0.f, 0.f, 0.f, 0.f};

    float4 ld[4];
#pragma unroll
    for (int p = 0; p < 4; ++p)
        ld[p] = *(const float4*)(Xb + (size_t)(lrow + 32 * p) * NN + lf * 4);

    // write buf 0
#pragma unroll
    for (int p = 0; p < 4; ++p) {
        const float4 v = ld[p];
        rs[p] += v.x + v.y + v.z + v.w;
        float f[4] = {v.x, v.y, v.z, v.w};
        s16x4 h, l;
#pragma unroll
        for (int r = 0; r < 4; ++r) {
            unsigned short hh = f2b(f[r]);
            h[r] = (short)hh;
            l[r] = (short)f2b(f[r] - b2f(hh));
        }
        const int off = (lrow + 32 * p) * SSTR + lf * 4;
        *(s16x4*)(&Xs[0][0][off]) = h;
        *(s16x4*)(&Xs[0][1][off]) = l;
    }
    __syncthreads();

    for (int kt = 0; kt < 14; ++kt) {
        const int cur = kt & 1;
        if (kt < 13) {
#pragma unroll
            for (int p = 0; p < 4; ++p)
                ld[p] = *(const float4*)(Xb + (size_t)(lrow + 32 * p) * NN + (kt + 1) * 32 + lf * 4);
        }
        // MFMA on buf cur
        s16x8 ah[4], al[4], bh[4], bl[4];
#pragma unroll
        for (int t = 0; t < 4; ++t) {
            ah[t] = *(const s16x8*)(&Xs[cur][0][(i0 + t * 16 + l15) * SSTR + q * 8]);
            al[t] = *(const s16x8*)(&Xs[cur][1][(i0 + t * 16 + l15) * SSTR + q * 8]);
            bh[t] = *(const s16x8*)(&Xs[cur][0][(j0 + t * 16 + l15) * SSTR + q * 8]);
            bl[t] = *(const s16x8*)(&Xs[cur][1][(j0 + t * 16 + l15) * SSTR + q * 8]);
        }
#pragma unroll
        for (int rt = 0; rt < 4; ++rt)
#pragma unroll
            for (int ct = 0; ct < 4; ++ct) {
                acc[rt][ct] = MF(ah[rt], bh[ct], acc[rt][ct]);
                acc[rt][ct] = MF(ah[rt], bl[ct], acc[rt][ct]);
                acc[rt][ct] = MF(al[rt], bh[ct], acc[rt][ct]);
            }
        if (kt < 13) {
#pragma unroll
            for (int p = 0; p < 4; ++p) {
                const float4 v = ld[p];
                rs[p] += v.x + v.y + v.z + v.w;
                float f[4] = {v.x, v.y, v.z, v.w};
                s16x4 h, l;
#pragma unroll
                for (int r = 0; r < 4; ++r) {
                    unsigned short hh = f2b(f[r]);
                    h[r] = (short)hh;
                    l[r] = (short)f2b(f[r] - b2f(hh));
                }
                const int off = (lrow + 32 * p) * SSTR + lf * 4;
                *(s16x4*)(&Xs[cur ^ 1][0][off]) = h;
                *(s16x4*)(&Xs[cur ^ 1][1][off]) = l;
            }
            __syncthreads();
        }
    }

    float* __restrict__ Gb = Gpart + (size_t)(ks * BB + b) * MATS;
#pragma unroll
    for (int rt = 0; rt < 4; ++rt)
#pragma unroll
        for (int ct = 0; ct < 4; ++ct)
#pragma unroll
            for (int r = 0; r < 4; ++r) {
                const int m = i0 + rt * 16 + q * 4 + r;
                const int n = j0 + ct * 16 + l15;
                Gb[m * CC + n] = acc[rt][ct][r];
            }
#pragma unroll
    for (int p = 0; p < 4; ++p) {
        float v = rs[p];
        v += __shfl_xor(v, 1);
        v += __shfl_xor(v, 2);
        v += __shfl_xor(v, 4);
        if ((lane & 7) == 0)
            rspart[(size_t)(ks * BB + b) * CC + lrow + 32 * p] = v;
    }
}

// ---------------------------------------------------------------------------
// Fused: stats (sigma, tr) -> 5 Newton-Schulz iterations in LDS -> triu out.
// grid (BB), block 256. Y split-bf16, D/Z single-bf16. All NS matrices are
// symmetric (polynomials of A), so transposed-packed LDS writes are valid.
// ---------------------------------------------------------------------------
__shared__ short g_dummy; // (nothing - placeholder removed below)

template<bool DUAL>
__device__ __forceinline__ void mm_pass(const short* __restrict__ A1,
                                        const short* __restrict__ A2,
                                        const short* __restrict__ Bp,
                                        int i0, int j0, int l15, int q,
                                        f32x4 acc[4][4])
{
#pragma unroll
    for (int k0 = 0; k0 < 128; k0 += 32) {
        s16x8 a1[4], a2[4], bb[4];
#pragma unroll
        for (int t = 0; t < 4; ++t) {
            a1[t] = *(const s16x8*)(A1 + (i0 + t * 16 + l15) * PSTR + k0 + q * 8);
            if (DUAL)
                a2[t] = *(const s16x8*)(A2 + (i0 + t * 16 + l15) * PSTR + k0 + q * 8);
            bb[t] = *(const s16x8*)(Bp + (j0 + t * 16 + l15) * PSTR + k0 + q * 8);
        }
#pragma unroll
        for (int rt = 0; rt < 4; ++rt)
#pragma unroll
            for (int ct = 0; ct < 4; ++ct) {
                acc[rt][ct] = MF(a1[rt], bb[ct], acc[rt][ct]);
                if (DUAL) acc[rt][ct] = MF(a2[rt], bb[ct], acc[rt][ct]);
            }
    }
}

__global__ __launch_bounds__(256, 1)
void ns_kernel(const float* __restrict__ Gpart, const float* __restrict__ rspart,
               float* __restrict__ out)
{
    __shared__ short Yhi[128 * PSTR];
    __shared__ short Ylo[128 * PSTR];
    __shared__ short Dm [128 * PSTR];
    __shared__ short Zm [128 * PSTR];
    __shared__ float mu[CC];
    __shared__ float red[256];

    const int b = blockIdx.x;
    const int tid  = threadIdx.x;
    const int wave = tid >> 6, lane = tid & 63;
    const int q = lane >> 4, l15 = lane & 15;
    const int i0 = (wave >> 1) * 64, j0 = (wave & 1) * 64;

    // ---- stats: mu ----
    if (tid < CC) {
        float s = 0.f;
#pragma unroll
        for (int ks = 0; ks < KS; ++ks)
            s += rspart[(size_t)(ks * BB + b) * CC + tid];
        mu[tid] = s * (1.0f / NN);
    }
    __syncthreads();

    // ---- stats: sigma (fp32 in regs), trace ----
    const float4* __restrict__ GP4 = (const float4*)Gpart;
    float4 sig[16];
    float trpart = 0.f;
#pragma unroll
    for (int jj = 0; jj < 16; jj += 4) {
        float4 tb[4][7];
#pragma unroll
        for (int j2 = 0; j2 < 4; ++j2) {
            const int idx4 = tid + 256 * (jj + j2);
#pragma unroll
            for (int ks = 0; ks < KS; ++ks)
                tb[j2][ks] = GP4[(size_t)(ks * BB + b) * 4096 + idx4];
        }
#pragma unroll
        for (int j2 = 0; j2 < 4; ++j2) {
            const int idx4 = tid + 256 * (jj + j2);
            const int row = idx4 >> 5;
            const int c4  = (idx4 & 31) << 2;
            float g[4] = {0.f, 0.f, 0.f, 0.f};
#pragma unroll
            for (int ks = 0; ks < KS; ++ks) {
                g[0] += tb[j2][ks].x; g[1] += tb[j2][ks].y;
                g[2] += tb[j2][ks].z; g[3] += tb[j2][ks].w;
            }
            float4 sv;
            const float mr = mu[row];
            sv.x = g[0] * (1.0f / NN) - mr * mu[c4 + 0];
            sv.y = g[1] * (1.0f / NN) - mr * mu[c4 + 1];
            sv.z = g[2] * (1.0f / NN) - mr * mu[c4 + 2];
            sv.w = g[3] * (1.0f / NN) - mr * mu[c4 + 3];
            sig[jj + j2] = sv;
            const int dd = row - c4;
            if (dd == 0) trpart += sv.x;
            else if (dd == 1) trpart += sv.y;
            else if (dd == 2) trpart += sv.z;
            else if (dd == 3) trpart += sv.w;
        }
    }
    red[tid] = trpart;
    __syncthreads();
    for (int s = 128; s > 0; s >>= 1) {
        if (tid < s) red[tid] += red[tid + s];
        __syncthreads();
    }
    const float tr = red[0];
    const float invtr = 1.0f / tr;
    const float sscale = sqrtf(tr);
    __syncthreads();

    // ---- write planes: Y1 = A = sigma/tr (split), D1 = 0.5I-0.5A, Z = I+D1 ----
#pragma unroll
    for (int jj = 0; jj < 16; ++jj) {
        const int idx4 = tid + 256 * jj;
        const int row = idx4 >> 5;
        const int c4  = (idx4 & 31) << 2;
        const float4 sv = sig[jj];
        float a[4] = {sv.x * invtr, sv.y * invtr, sv.z * invtr, sv.w * invtr};
        s16x4 yh, yl, dv, zv;
#pragma unroll
        for (int r = 0; r < 4; ++r) {
            unsigned short hh = f2b(a[r]);
            yh[r] = (short)hh;
            yl[r] = (short)f2b(a[r] - b2f(hh));
            const float dia = (row == c4 + r) ? 0.5f : 0.0f;
            const float d = dia - 0.5f * a[r];
            dv[r] = (short)f2b(d);
            zv[r] = (short)f2b(((row == c4 + r) ? 1.0f : 0.0f) + d);
        }
        const int off = row * PSTR + c4;
        *(s16x4*)(&Yhi[off]) = yh;
        *(s16x4*)(&Ylo[off]) = yl;
        *(s16x4*)(&Dm[off])  = dv;
        *(s16x4*)(&Zm[off])  = zv;
    }
    __syncthreads();

    f32x4 acc[4][4];

    // ---- iteration 1: P2 only (Y2 = Y1 + Y1@D1); Z already = T1 ----
#pragma unroll
    for (int rt = 0; rt < 4; ++rt)
#pragma unroll
        for (int ct = 0; ct < 4; ++ct) acc[rt][ct] = (f32x4){0.f, 0.f, 0.f, 0.f};
    mm_pass<true>(Yhi, Ylo, Dm, i0, j0, l15, q, acc);
    __syncthreads();
#pragma unroll
    for (int rt = 0; rt < 4; ++rt)
#pragma unroll
        for (int ct = 0; ct < 4; ++ct) {
            const int m0 = i0 + rt * 16 + q * 4;
            const int n  = j0 + ct * 16 + l15;
            const int off = n * PSTR + m0;
            s16x4 yh = *(s16x4*)(&Yhi[off]);
            s16x4 yl = *(s16x4*)(&Ylo[off]);
            s16x4 nh, nl;
#pragma unroll
            for (int r = 0; r < 4; ++r) {
                const float y = acc[rt][ct][r] + b2f((unsigned short)yh[r]) + b2f((unsigned short)yl[r]);
                unsigned short hh = f2b(y);
                nh[r] = (short)hh;
                nl[r] = (short)f2b(y - b2f(hh));
            }
            *(s16x4*)(&Yhi[off]) = nh;
            *(s16x4*)(&Ylo[off]) = nl;
        }
    __syncthreads();

    // ---- iterations 2..5 ----
    for (int it = 2; it <= 5; ++it) {
        // P1: D = 0.5I - 0.5 * Z@Y   (Y approximated by Yhi: damped path)
#pragma unroll
        for (int rt = 0; rt < 4; ++rt)
#pragma unroll
            for (int ct = 0; ct < 4; ++ct) acc[rt][ct] = (f32x4){0.f, 0.f, 0.f, 0.f};
        mm_pass<false>(Zm, Zm, Yhi, i0, j0, l15, q, acc);
        // D writes don't collide with P1 operand reads (different planes)
#pragma unroll
        for (int rt = 0; rt < 4; ++rt)
#pragma unroll
            for (int ct = 0; ct < 4; ++ct) {
                const int m0 = i0 + rt * 16 + q * 4;
                const int n  = j0 + ct * 16 + l15;
                s16x4 dv;
#pragma unroll
                for (int r = 0; r < 4; ++r) {
                    const float dia = (m0 + r == n) ? 0.5f : 0.0f;
                    dv[r] = (short)f2b(dia - 0.5f * acc[rt][ct][r]);
                }
                *(s16x4*)(&Dm[n * PSTR + m0]) = dv;
            }
        __syncthreads();

        // P2: Ynew = Y + Y@D  (Y split)
#pragma unroll
        for (int rt = 0; rt < 4; ++rt)
#pragma unroll
            for (int ct = 0; ct < 4; ++ct) acc[rt][ct] = (f32x4){0.f, 0.f, 0.f, 0.f};
        mm_pass<true>(Yhi, Ylo, Dm, i0, j0, l15, q, acc);
        __syncthreads();

        if (it < 5) {
#pragma unroll
            for (int rt = 0; rt < 4; ++rt)
#pragma unroll
                for (int ct = 0; ct < 4; ++ct) {
                    const int m0 = i0 + rt * 16 + q * 4;
                    const int n  = j0 + ct * 16 + l15;
                    const int off = n * PSTR + m0;
                    s16x4 yh = *(s16x4*)(&Yhi[off]);
                    s16x4 yl = *(s16x4*)(&Ylo[off]);
                    s16x4 nh, nl;
#pragma unroll
                    for (int r = 0; r < 4; ++r) {
                        const float y = acc[rt][ct][r] + b2f((unsigned short)yh[r]) + b2f((unsigned short)yl[r]);
                        unsigned short hh = f2b(y);
                        nh[r] = (short)hh;
                        nl[r] = (short)f2b(y - b2f(hh));
                    }
                    *(s16x4*)(&Yhi[off]) = nh;
                    *(s16x4*)(&Ylo[off]) = nl;
                }
            __syncthreads();

            // P3: Znew = Z + D@Z
#pragma unroll
            for (int rt = 0; rt < 4; ++rt)
#pragma unroll
                for (int ct = 0; ct < 4; ++ct) acc[rt][ct] = (f32x4){0.f, 0.f, 0.f, 0.f};
            mm_pass<false>(Dm, Dm, Zm, i0, j0, l15, q, acc);
            __syncthreads();
#pragma unroll
            for (int rt = 0; rt < 4; ++rt)
#pragma unroll
                for (int ct = 0; ct < 4; ++ct) {
                    const int m0 = i0 + rt * 16 + q * 4;
                    const int n  = j0 + ct * 16 + l15;
                    const int off = n * PSTR + m0;
                    s16x4 zv = *(s16x4*)(&Zm[off]);
                    s16x4 zn;
#pragma unroll
                    for (int r = 0; r < 4; ++r) {
                        const float z = acc[rt][ct][r] + b2f((unsigned short)zv[r]);
                        zn[r] = (short)f2b(z);
                    }
                    *(s16x4*)(&Zm[off]) = zn;
                }
            __syncthreads();
        } else {
            // final: out = triu(Y6) * sqrt(tr)
            float* __restrict__ ob = out + (size_t)b * OUTLEN;
#pragma unroll
            for (int rt = 0; rt < 4; ++rt)
#pragma unroll
                for (int ct = 0; ct < 4; ++ct) {
                    const int m0 = i0 + rt * 16 + q * 4;
                    const int n  = j0 + ct * 16 + l15;
                    const int off = n * PSTR + m0;
                    s16x4 yh = *(s16x4*)(&Yhi[off]);
                    s16x4 yl = *(s16x4*)(&Ylo[off]);
#pragma unroll
                    for (int r = 0; r < 4; ++r) {
                        const int m = m0 + r;
                        if (m <= n) {
                            const float y = acc[rt][ct][r] + b2f((unsigned short)yh[r]) + b2f((unsigned short)yl[r]);
                            ob[m * CC - ((m * (m - 1)) >> 1) + (n - m)] = y * sscale;
                        }
                    }
                }
        }
    }
}

extern "C" void kernel_launch(void* const* d_in, const int* in_sizes, int n_in,
                              void* d_out, int out_size, void* d_ws, size_t ws_size,
                              hipStream_t stream)
{
    (void)in_sizes; (void)n_in; (void)out_size; (void)ws_size;
    const float* x = (const float*)d_in[0];
    float* out = (float*)d_out;
    float* ws  = (float*)d_ws;

    float* rspart = ws;                       // KS*BB*CC = 57344 floats
    float* Gpart  = ws + (size_t)KS * BB * CC; // KS*BB*MATS floats

    gram_kernel<<<dim3(BB, KS), 256, 0, stream>>>(x, Gpart, rspart);
    ns_kernel<<<dim3(BB), 256, 0, stream>>>(Gpart, rspart, out);
}

// Round 3
// 189.836 us; speedup vs baseline: 1.9476x; 1.0580x over previous
//
#include <hip/hip_runtime.h>
#include <math.h>

// iSQRT-COV: B=64, C=128, n=3136.
// sigma = G/n - mu mu^T (G = X X^T via split-bf16 MFMA),
// fused Newton-Schulz (5 iters) entirely in LDS, one 1024-thread block/batch.

#define CC 128
#define NN 3136
#define BB 64
#define KS 7
#define KCHUNK 448            // NN/KS = 14 ksteps of 32
#define MATS (CC * CC)
#define OUTLEN 8256
#define PSTR 136              // ns plane row stride in bf16 (68 dwords: 2-way max on frag reads)
#define SSTR 34               // gram stage row stride in bf16 (17 dwords, odd: spreads banks)

typedef float f32x4 __attribute__((ext_vector_type(4)));
typedef short s16x8 __attribute__((ext_vector_type(8)));
typedef short s16x4 __attribute__((ext_vector_type(4)));
typedef __bf16 bf16x8 __attribute__((ext_vector_type(8)));

__device__ __forceinline__ unsigned short f2b(float f) {
    unsigned u = __builtin_bit_cast(unsigned, f);
    unsigned r = u + 0x7fffu + ((u >> 16) & 1u);
    return (unsigned short)(r >> 16);
}
__device__ __forceinline__ float b2f(unsigned short s) {
    return __builtin_bit_cast(float, ((unsigned)s) << 16);
}

__device__ __forceinline__ f32x4 MF(s16x8 a, s16x8 b, f32x4 c) {
    return __builtin_amdgcn_mfma_f32_16x16x32_bf16(
        __builtin_bit_cast(bf16x8, a), __builtin_bit_cast(bf16x8, b), c, 0, 0, 0);
}

// ---------------------------------------------------------------------------
// Gram partial via split-bf16 MFMA. grid (BB, KS), block 256 (4 waves).
// ---------------------------------------------------------------------------
__global__ __launch_bounds__(256, 2)
void gram_kernel(const float* __restrict__ x, float* __restrict__ Gpart,
                 float* __restrict__ rspart)
{
    __shared__ short Xs[2][2][128 * SSTR];   // [buf][hi/lo][row*SSTR+k]
    const int b = blockIdx.x, ks = blockIdx.y;
    const int tid  = threadIdx.x;
    const int wave = tid >> 6, lane = tid & 63;
    const int q = lane >> 4, l15 = lane & 15;
    const int i0 = (wave >> 1) * 64, j0 = (wave & 1) * 64;

    const float* __restrict__ Xb = x + (size_t)b * CC * NN + (size_t)ks * KCHUNK;
    const int lrow = tid >> 3;        // 0..31
    const int lf   = tid & 7;         // 0..7

    f32x4 acc[4][4];
#pragma unroll
    for (int rt = 0; rt < 4; ++rt)
#pragma unroll
        for (int ct = 0; ct < 4; ++ct) acc[rt][ct] = (f32x4){0.f, 0.f, 0.f, 0.f};
    float rs[4] = {0.f, 0.f, 0.f, 0.f};

    float4 ld[4];
#pragma unroll
    for (int p = 0; p < 4; ++p)
        ld[p] = *(const float4*)(Xb + (size_t)(lrow + 32 * p) * NN + lf * 4);

#pragma unroll
    for (int p = 0; p < 4; ++p) {
        const float4 v = ld[p];
        rs[p] += v.x + v.y + v.z + v.w;
        float f[4] = {v.x, v.y, v.z, v.w};
        s16x4 h, l;
#pragma unroll
        for (int r = 0; r < 4; ++r) {
            unsigned short hh = f2b(f[r]);
            h[r] = (short)hh;
            l[r] = (short)f2b(f[r] - b2f(hh));
        }
        const int off = (lrow + 32 * p) * SSTR + lf * 4;
        *(s16x4*)(&Xs[0][0][off]) = h;
        *(s16x4*)(&Xs[0][1][off]) = l;
    }
    __syncthreads();

    for (int kt = 0; kt < 14; ++kt) {
        const int cur = kt & 1;
        if (kt < 13) {
#pragma unroll
            for (int p = 0; p < 4; ++p)
                ld[p] = *(const float4*)(Xb + (size_t)(lrow + 32 * p) * NN + (kt + 1) * 32 + lf * 4);
        }
        s16x8 ah[4], al[4], bh[4], bl[4];
#pragma unroll
        for (int t = 0; t < 4; ++t) {
            ah[t] = *(const s16x8*)(&Xs[cur][0][(i0 + t * 16 + l15) * SSTR + q * 8]);
            al[t] = *(const s16x8*)(&Xs[cur][1][(i0 + t * 16 + l15) * SSTR + q * 8]);
            bh[t] = *(const s16x8*)(&Xs[cur][0][(j0 + t * 16 + l15) * SSTR + q * 8]);
            bl[t] = *(const s16x8*)(&Xs[cur][1][(j0 + t * 16 + l15) * SSTR + q * 8]);
        }
#pragma unroll
        for (int rt = 0; rt < 4; ++rt)
#pragma unroll
            for (int ct = 0; ct < 4; ++ct) {
                acc[rt][ct] = MF(ah[rt], bh[ct], acc[rt][ct]);
                acc[rt][ct] = MF(ah[rt], bl[ct], acc[rt][ct]);
                acc[rt][ct] = MF(al[rt], bh[ct], acc[rt][ct]);
            }
        if (kt < 13) {
#pragma unroll
            for (int p = 0; p < 4; ++p) {
                const float4 v = ld[p];
                rs[p] += v.x + v.y + v.z + v.w;
                float f[4] = {v.x, v.y, v.z, v.w};
                s16x4 h, l;
#pragma unroll
                for (int r = 0; r < 4; ++r) {
                    unsigned short hh = f2b(f[r]);
                    h[r] = (short)hh;
                    l[r] = (short)f2b(f[r] - b2f(hh));
                }
                const int off = (lrow + 32 * p) * SSTR + lf * 4;
                *(s16x4*)(&Xs[cur ^ 1][0][off]) = h;
                *(s16x4*)(&Xs[cur ^ 1][1][off]) = l;
            }
            __syncthreads();
        }
    }

    float* __restrict__ Gb = Gpart + (size_t)(ks * BB + b) * MATS;
#pragma unroll
    for (int rt = 0; rt < 4; ++rt)
#pragma unroll
        for (int ct = 0; ct < 4; ++ct)
#pragma unroll
            for (int r = 0; r < 4; ++r) {
                const int m = i0 + rt * 16 + q * 4 + r;
                const int n = j0 + ct * 16 + l15;
                Gb[m * CC + n] = acc[rt][ct][r];
            }
#pragma unroll
    for (int p = 0; p < 4; ++p) {
        float v = rs[p];
        v += __shfl_xor(v, 1);
        v += __shfl_xor(v, 2);
        v += __shfl_xor(v, 4);
        if ((lane & 7) == 0)
            rspart[(size_t)(ks * BB + b) * CC + lrow + 32 * p] = v;
    }
}

// ---------------------------------------------------------------------------
// Fused NS: 1024 threads (16 waves), each wave owns a 32x32 tile (2x2 frags).
// Y split-bf16, D/Z single-bf16; all NS matrices symmetric -> transposed
// packed epilogue writes are valid.
// ---------------------------------------------------------------------------
template<bool DUAL>
__device__ __forceinline__ void mm_pass(const short* __restrict__ A1,
                                        const short* __restrict__ A2,
                                        const short* __restrict__ Bp,
                                        int i0, int j0, int l15, int q,
                                        f32x4 acc[2][2])
{
#pragma unroll
    for (int k0 = 0; k0 < 128; k0 += 32) {
        s16x8 a1[2], a2[2], bb[2];
#pragma unroll
        for (int t = 0; t < 2; ++t) {
            a1[t] = *(const s16x8*)(A1 + (i0 + t * 16 + l15) * PSTR + k0 + q * 8);
            if (DUAL)
                a2[t] = *(const s16x8*)(A2 + (i0 + t * 16 + l15) * PSTR + k0 + q * 8);
            bb[t] = *(const s16x8*)(Bp + (j0 + t * 16 + l15) * PSTR + k0 + q * 8);
        }
#pragma unroll
        for (int rt = 0; rt < 2; ++rt)
#pragma unroll
            for (int ct = 0; ct < 2; ++ct) {
                acc[rt][ct] = MF(a1[rt], bb[ct], acc[rt][ct]);
                if (DUAL) acc[rt][ct] = MF(a2[rt], bb[ct], acc[rt][ct]);
            }
    }
}

__global__ __launch_bounds__(1024, 4)
void ns_kernel(const float* __restrict__ Gpart, const float* __restrict__ rspart,
               float* __restrict__ out)
{
    __shared__ short Yhi[128 * PSTR];
    __shared__ short Ylo[128 * PSTR];
    __shared__ short Dm [128 * PSTR];
    __shared__ short Zm [128 * PSTR];
    __shared__ float mu[CC];
    __shared__ float red[32];

    const int b = blockIdx.x;
    const int tid  = threadIdx.x;
    const int wave = tid >> 6, lane = tid & 63;
    const int q = lane >> 4, l15 = lane & 15;
    const int i0 = (wave >> 2) * 32, j0 = (wave & 3) * 32;

    // ---- mu ----
    if (tid < CC) {
        float s = 0.f;
#pragma unroll
        for (int ks = 0; ks < KS; ++ks)
            s += rspart[(size_t)(ks * BB + b) * CC + tid];
        mu[tid] = s * (1.0f / NN);
    }
    __syncthreads();

    // ---- sigma (4 float4/thread) + trace ----
    const float4* __restrict__ GP4 = (const float4*)Gpart;
    float4 sig[4];
    float trpart = 0.f;
#pragma unroll
    for (int jj = 0; jj < 4; ++jj) {
        const int idx4 = tid + 1024 * jj;
        float4 tb[KS];
#pragma unroll
        for (int ks = 0; ks < KS; ++ks)
            tb[ks] = GP4[(size_t)(ks * BB + b) * 4096 + idx4];
        const int row = idx4 >> 5;
        const int c4  = (idx4 & 31) << 2;
        float g[4] = {0.f, 0.f, 0.f, 0.f};
#pragma unroll
        for (int ks = 0; ks < KS; ++ks) {
            g[0] += tb[ks].x; g[1] += tb[ks].y;
            g[2] += tb[ks].z; g[3] += tb[ks].w;
        }
        float4 sv;
        const float mr = mu[row];
        sv.x = g[0] * (1.0f / NN) - mr * mu[c4 + 0];
        sv.y = g[1] * (1.0f / NN) - mr * mu[c4 + 1];
        sv.z = g[2] * (1.0f / NN) - mr * mu[c4 + 2];
        sv.w = g[3] * (1.0f / NN) - mr * mu[c4 + 3];
        sig[jj] = sv;
        const int dd = row - c4;
        if (dd == 0) trpart += sv.x;
        else if (dd == 1) trpart += sv.y;
        else if (dd == 2) trpart += sv.z;
        else if (dd == 3) trpart += sv.w;
    }
    // wave-level reduce, then broadcast via LDS
    trpart += __shfl_xor(trpart, 1);
    trpart += __shfl_xor(trpart, 2);
    trpart += __shfl_xor(trpart, 4);
    trpart += __shfl_xor(trpart, 8);
    trpart += __shfl_xor(trpart, 16);
    trpart += __shfl_xor(trpart, 32);
    if (lane == 0) red[wave] = trpart;
    __syncthreads();
    float tr = 0.f;
#pragma unroll
    for (int w = 0; w < 16; ++w) tr += red[w];
    const float invtr = 1.0f / tr;
    const float sscale = sqrtf(tr);

    // ---- planes: Y1 = A (split), D1 = 0.5I-0.5A, Z = I+D1 ----
#pragma unroll
    for (int jj = 0; jj < 4; ++jj) {
        const int idx4 = tid + 1024 * jj;
        const int row = idx4 >> 5;
        const int c4  = (idx4 & 31) << 2;
        const float4 sv = sig[jj];
        float a[4] = {sv.x * invtr, sv.y * invtr, sv.z * invtr, sv.w * invtr};
        s16x4 yh, yl, dv, zv;
#pragma unroll
        for (int r = 0; r < 4; ++r) {
            unsigned short hh = f2b(a[r]);
            yh[r] = (short)hh;
            yl[r] = (short)f2b(a[r] - b2f(hh));
            const float dia = (row == c4 + r) ? 0.5f : 0.0f;
            const float d = dia - 0.5f * a[r];
            dv[r] = (short)f2b(d);
            zv[r] = (short)f2b(((row == c4 + r) ? 1.0f : 0.0f) + d);
        }
        const int off = row * PSTR + c4;
        *(s16x4*)(&Yhi[off]) = yh;
        *(s16x4*)(&Ylo[off]) = yl;
        *(s16x4*)(&Dm[off])  = dv;
        *(s16x4*)(&Zm[off])  = zv;
    }
    __syncthreads();

    f32x4 acc[2][2];

    // ---- iter 1: Y2 = Y1 + Y1@D1 (Z already = T1) ----
#pragma unroll
    for (int rt = 0; rt < 2; ++rt)
#pragma unroll
        for (int ct = 0; ct < 2; ++ct) acc[rt][ct] = (f32x4){0.f, 0.f, 0.f, 0.f};
    mm_pass<true>(Yhi, Ylo, Dm, i0, j0, l15, q, acc);
    __syncthreads();
#pragma unroll
    for (int rt = 0; rt < 2; ++rt)
#pragma unroll
        for (int ct = 0; ct < 2; ++ct) {
            const int m0 = i0 + rt * 16 + q * 4;
            const int n  = j0 + ct * 16 + l15;
            const int off = n * PSTR + m0;
            s16x4 yh = *(s16x4*)(&Yhi[off]);
            s16x4 yl = *(s16x4*)(&Ylo[off]);
            s16x4 nh, nl;
#pragma unroll
            for (int r = 0; r < 4; ++r) {
                const float y = acc[rt][ct][r] + b2f((unsigned short)yh[r]) + b2f((unsigned short)yl[r]);
                unsigned short hh = f2b(y);
                nh[r] = (short)hh;
                nl[r] = (short)f2b(y - b2f(hh));
            }
            *(s16x4*)(&Yhi[off]) = nh;
            *(s16x4*)(&Ylo[off]) = nl;
        }
    __syncthreads();

    // ---- iters 2..5 ----
    for (int it = 2; it <= 5; ++it) {
        // P1: D = 0.5I - 0.5 * Z@Y (Y ~ Yhi: damped path)
#pragma unroll
        for (int rt = 0; rt < 2; ++rt)
#pragma unroll
            for (int ct = 0; ct < 2; ++ct) acc[rt][ct] = (f32x4){0.f, 0.f, 0.f, 0.f};
        mm_pass<false>(Zm, Zm, Yhi, i0, j0, l15, q, acc);
#pragma unroll
        for (int rt = 0; rt < 2; ++rt)
#pragma unroll
            for (int ct = 0; ct < 2; ++ct) {
                const int m0 = i0 + rt * 16 + q * 4;
                const int n  = j0 + ct * 16 + l15;
                s16x4 dv;
#pragma unroll
                for (int r = 0; r < 4; ++r) {
                    const float dia = (m0 + r == n) ? 0.5f : 0.0f;
                    dv[r] = (short)f2b(dia - 0.5f * acc[rt][ct][r]);
                }
                *(s16x4*)(&Dm[n * PSTR + m0]) = dv;
            }
        __syncthreads();

        // P2: Ynew = Y + Y@D (split)
#pragma unroll
        for (int rt = 0; rt < 2; ++rt)
#pragma unroll
            for (int ct = 0; ct < 2; ++ct) acc[rt][ct] = (f32x4){0.f, 0.f, 0.f, 0.f};
        mm_pass<true>(Yhi, Ylo, Dm, i0, j0, l15, q, acc);
        __syncthreads();

        if (it < 5) {
#pragma unroll
            for (int rt = 0; rt < 2; ++rt)
#pragma unroll
                for (int ct = 0; ct < 2; ++ct) {
                    const int m0 = i0 + rt * 16 + q * 4;
                    const int n  = j0 + ct * 16 + l15;
                    const int off = n * PSTR + m0;
                    s16x4 yh = *(s16x4*)(&Yhi[off]);
                    s16x4 yl = *(s16x4*)(&Ylo[off]);
                    s16x4 nh, nl;
#pragma unroll
                    for (int r = 0; r < 4; ++r) {
                        const float y = acc[rt][ct][r] + b2f((unsigned short)yh[r]) + b2f((unsigned short)yl[r]);
                        unsigned short hh = f2b(y);
                        nh[r] = (short)hh;
                        nl[r] = (short)f2b(y - b2f(hh));
                    }
                    *(s16x4*)(&Yhi[off]) = nh;
                    *(s16x4*)(&Ylo[off]) = nl;
                }
            __syncthreads();

            // P3: Znew = Z + D@Z
#pragma unroll
            for (int rt = 0; rt < 2; ++rt)
#pragma unroll
                for (int ct = 0; ct < 2; ++ct) acc[rt][ct] = (f32x4){0.f, 0.f, 0.f, 0.f};
            mm_pass<false>(Dm, Dm, Zm, i0, j0, l15, q, acc);
            __syncthreads();
#pragma unroll
            for (int rt = 0; rt < 2; ++rt)
#pragma unroll
                for (int ct = 0; ct < 2; ++ct) {
                    const int m0 = i0 + rt * 16 + q * 4;
                    const int n  = j0 + ct * 16 + l15;
                    const int off = n * PSTR + m0;
                    s16x4 zv = *(s16x4*)(&Zm[off]);
                    s16x4 zn;
#pragma unroll
                    for (int r = 0; r < 4; ++r) {
                        const float z = acc[rt][ct][r] + b2f((unsigned short)zv[r]);
                        zn[r] = (short)f2b(z);
                    }
                    *(s16x4*)(&Zm[off]) = zn;
                }
            __syncthreads();
        } else {
            // out = triu(Y6) * sqrt(tr)
            float* __restrict__ ob = out + (size_t)b * OUTLEN;
#pragma unroll
            for (int rt = 0; rt < 2; ++rt)
#pragma unroll
                for (int ct = 0; ct < 2; ++ct) {
                    const int m0 = i0 + rt * 16 + q * 4;
                    const int n  = j0 + ct * 16 + l15;
                    const int off = n * PSTR + m0;
                    s16x4 yh = *(s16x4*)(&Yhi[off]);
                    s16x4 yl = *(s16x4*)(&Ylo[off]);
#pragma unroll
                    for (int r = 0; r < 4; ++r) {
                        const int m = m0 + r;
                        if (m <= n) {
                            const float y = acc[rt][ct][r] + b2f((unsigned short)yh[r]) + b2f((unsigned short)yl[r]);
                            ob[m * CC - ((m * (m - 1)) >> 1) + (n - m)] = y * sscale;
                        }
                    }
                }
        }
    }
}

extern "C" void kernel_launch(void* const* d_in, const int* in_sizes, int n_in,
                              void* d_out, int out_size, void* d_ws, size_t ws_size,
                              hipStream_t stream)
{
    (void)in_sizes; (void)n_in; (void)out_size; (void)ws_size;
    const float* x = (const float*)d_in[0];
    float* out = (float*)d_out;
    float* ws  = (float*)d_ws;

    float* rspart = ws;                        // KS*BB*CC floats
    float* Gpart  = ws + (size_t)KS * BB * CC; // KS*BB*MATS floats

    gram_kernel<<<dim3(BB, KS), 256, 0, stream>>>(x, Gpart, rspart);
    ns_kernel<<<dim3(BB), 1024, 0, stream>>>(Gpart, rspart, out);
}